// Round 6
// baseline (226.070 us; speedup 1.0000x reference)
//
#include <hip/hip_runtime.h>
#include <hip/hip_bf16.h>

#define EPSV 1e-3f

__device__ __forceinline__ float rcp_fast(float x){ return __builtin_amdgcn_rcpf(x); }
__device__ __forceinline__ float sigm(float x){ return rcp_fast(1.f + __expf(-x)); }
__device__ __forceinline__ float tanh_fast(float x){
    float e = __expf(2.f * x);
    return 1.f - 2.f * rcp_fast(e + 1.f);
}
__device__ __forceinline__ float wave_sum(float v){
    v += __shfl_xor(v, 1);  v += __shfl_xor(v, 2);  v += __shfl_xor(v, 4);
    v += __shfl_xor(v, 8);  v += __shfl_xor(v, 16); v += __shfl_xor(v, 32);
    return v;
}

// ============ K1: stage-1 LSTM (tanh), ONE LANE PER SAMPLE =================
// All weight indices are wave-uniform -> s_load + v_fma(SGPR weight) ; weights
// consume ZERO VGPRs (R2-R5 evidence: lane-indexed weights always get
// rematerialized/spilled). 32 gate columns accumulated as 32 independent
// FMA chains in VGPRs.
__global__ __launch_bounds__(256)
__attribute__((amdgpu_waves_per_eu(1, 4)))
void k1_lstm0(const float* __restrict__ noise, const float* __restrict__ W0,
              const float* __restrict__ U0, const float* __restrict__ b0,
              float* __restrict__ Hbuf, float* __restrict__ Cbuf,
              double* __restrict__ stats1)
{
    const int tid = threadIdx.x;
    const size_t s = (size_t)blockIdx.x * 256 + tid;
    const float4* __restrict__ xr = reinterpret_cast<const float4*>(noise + s * 512);

    float h[8], c[8];
    #pragma unroll
    for (int u = 0; u < 8; ++u){ h[u] = 0.f; c[u] = 0.f; }

    // prefetch t=0
    float4 p0 = xr[0], p1 = xr[1], p2 = xr[2], p3 = xr[3];

    #pragma unroll 1
    for (int t = 0; t < 32; ++t){
        const float x[16] = {p0.x,p0.y,p0.z,p0.w, p1.x,p1.y,p1.z,p1.w,
                             p2.x,p2.y,p2.z,p2.w, p3.x,p3.y,p3.z,p3.w};
        const int tn = (t + 1) & 31;                 // harmless wrap prefetch
        p0 = xr[tn*4+0]; p1 = xr[tn*4+1]; p2 = xr[tn*4+2]; p3 = xr[tn*4+3];

        float z[32];
        #pragma unroll
        for (int col = 0; col < 32; ++col) z[col] = b0[col];
        #pragma unroll
        for (int f = 0; f < 16; ++f){
            const float xv = x[f];
            #pragma unroll
            for (int col = 0; col < 32; ++col) z[col] = fmaf(xv, W0[f*32 + col], z[col]);
        }
        #pragma unroll
        for (int e = 0; e < 8; ++e){
            const float hv = h[e];
            #pragma unroll
            for (int col = 0; col < 32; ++col) z[col] = fmaf(hv, U0[e*32 + col], z[col]);
        }
        // gates: i=z[0..7], f=z[8..15], g=z[16..23], o=z[24..31]
        #pragma unroll
        for (int u = 0; u < 8; ++u){
            c[u] = fmaf(sigm(z[8+u]), c[u], sigm(z[u]) * tanh_fast(z[16+u]));
            h[u] = sigm(z[24+u]) * tanh_fast(c[u]);
        }
    }

    // coalesced state dump: lane l owns 8 consecutive floats
    float4* Hv = reinterpret_cast<float4*>(Hbuf + s * 8);
    float4* Cv = reinterpret_cast<float4*>(Cbuf + s * 8);
    Hv[0] = make_float4(h[0],h[1],h[2],h[3]); Hv[1] = make_float4(h[4],h[5],h[6],h[7]);
    Cv[0] = make_float4(c[0],c[1],c[2],c[3]); Cv[1] = make_float4(c[4],c[5],c[6],c[7]);

    // BN1 stats: 32 per-unit sums (Sh, Sh2, Sc, Sc2)
    __shared__ float red[4][32];
    const int wv = tid >> 6, ln = tid & 63;
    #pragma unroll
    for (int u = 0; u < 8; ++u){
        const float a0 = wave_sum(h[u]);
        const float a1 = wave_sum(h[u]*h[u]);
        const float a2 = wave_sum(c[u]);
        const float a3 = wave_sum(c[u]*c[u]);
        if (ln == 0){ red[wv][u] = a0; red[wv][8+u] = a1; red[wv][16+u] = a2; red[wv][24+u] = a3; }
    }
    __syncthreads();
    if (tid < 32){
        const float acc = red[0][tid] + red[1][tid] + red[2][tid] + red[3][tid];
        atomicAdd(stats1 + tid, (double)acc);
    }
}

// ============ K2: BN1-apply + 14-step AR LSTM (relu), BN3 sums =============
__global__ __launch_bounds__(256)
__attribute__((amdgpu_waves_per_eu(1, 4)))
void k2_ar(const float* __restrict__ Hbuf, const float* __restrict__ Cbuf,
           const double* __restrict__ stats1,
           const float* __restrict__ gamma_h, const float* __restrict__ beta_h,
           const float* __restrict__ gamma_c, const float* __restrict__ beta_c,
           const float* __restrict__ W1, const float* __restrict__ U1,
           const float* __restrict__ b1, double* __restrict__ stats3, int B)
{
    const int tid = threadIdx.x;
    const size_t s = (size_t)blockIdx.x * 256 + tid;

    float h[8], c[8];
    {
        const float4* Hv = reinterpret_cast<const float4*>(Hbuf + s * 8);
        const float4* Cv = reinterpret_cast<const float4*>(Cbuf + s * 8);
        float4 a = Hv[0], b = Hv[1], d = Cv[0], e = Cv[1];
        h[0]=a.x;h[1]=a.y;h[2]=a.z;h[3]=a.w; h[4]=b.x;h[5]=b.y;h[6]=b.z;h[7]=b.w;
        c[0]=d.x;c[1]=d.y;c[2]=d.z;c[3]=d.w; c[4]=e.x;c[5]=e.y;c[6]=e.z;c[7]=e.w;
    }
    const double invB = 1.0 / (double)B;
    #pragma unroll
    for (int u = 0; u < 8; ++u){
        const float mH = (float)(stats1[u]      * invB);
        const float eH = (float)(stats1[8 + u]  * invB);
        const float mC = (float)(stats1[16 + u] * invB);
        const float eC = (float)(stats1[24 + u] * invB);
        const float aH = gamma_h[u] * rsqrtf(eH - mH*mH + EPSV);
        const float aC = gamma_c[u] * rsqrtf(eC - mC*mC + EPSV);
        h[u] = fmaf(h[u], aH, beta_h[u] - mH*aH);
        c[u] = fmaf(c[u], aC, beta_c[u] - mC*aC);
    }

    float s1[8], s2[8];
    #pragma unroll
    for (int u = 0; u < 8; ++u){ s1[u] = 0.f; s2[u] = 0.f; }

    #pragma unroll 1
    for (int r = 0; r < 14; ++r){
        float z[32];
        #pragma unroll
        for (int col = 0; col < 32; ++col) z[col] = b1[col];
        #pragma unroll
        for (int e = 0; e < 8; ++e){
            const float hv = h[e];
            #pragma unroll
            for (int col = 0; col < 32; ++col) z[col] = fmaf(hv, W1[e*32 + col], z[col]);
            #pragma unroll
            for (int col = 0; col < 32; ++col) z[col] = fmaf(hv, U1[e*32 + col], z[col]);
        }
        #pragma unroll
        for (int u = 0; u < 8; ++u){
            c[u] = fmaf(sigm(z[8+u]), c[u], sigm(z[u]) * fmaxf(z[16+u], 0.f));
            h[u] = sigm(z[24+u]) * fmaxf(c[u], 0.f);
            s1[u] += h[u]; s2[u] = fmaf(h[u], h[u], s2[u]);
        }
    }

    __shared__ float red[4][16];
    const int wv = tid >> 6, ln = tid & 63;
    #pragma unroll
    for (int u = 0; u < 8; ++u){
        const float a0 = wave_sum(s1[u]);
        const float a1 = wave_sum(s2[u]);
        if (ln == 0){ red[wv][u] = a0; red[wv][8+u] = a1; }
    }
    __syncthreads();
    if (tid < 16){
        const float acc = red[0][tid] + red[1][tid] + red[2][tid] + red[3][tid];
        atomicAdd(stats3 + tid, (double)acc);
    }
}

// ============ K3: AR replay + BN3 + backward output LSTM (8->4) ============
// bars[14][8] per lane live in LDS (lane-private slots, conflict-free,
// no barriers needed). Block = 64 threads -> 28 KB LDS, 4 blocks/CU.
__global__ __launch_bounds__(64)
__attribute__((amdgpu_waves_per_eu(1, 4)))
void k3_out(const float* __restrict__ Hbuf, const float* __restrict__ Cbuf,
            const double* __restrict__ stats1, const double* __restrict__ stats3,
            const float* __restrict__ gamma_h, const float* __restrict__ beta_h,
            const float* __restrict__ gamma_c, const float* __restrict__ beta_c,
            const float* __restrict__ W1, const float* __restrict__ U1,
            const float* __restrict__ b1,
            const float* __restrict__ gamma3, const float* __restrict__ beta3,
            const float* __restrict__ W2, const float* __restrict__ U2,
            const float* __restrict__ b2, float* __restrict__ out, int B)
{
    __shared__ float bars[14][8][64];
    const int tid = threadIdx.x;            // 0..63
    const size_t s = (size_t)blockIdx.x * 64 + tid;

    float h[8], c[8];
    {
        const float4* Hv = reinterpret_cast<const float4*>(Hbuf + s * 8);
        const float4* Cv = reinterpret_cast<const float4*>(Cbuf + s * 8);
        float4 a = Hv[0], b = Hv[1], d = Cv[0], e = Cv[1];
        h[0]=a.x;h[1]=a.y;h[2]=a.z;h[3]=a.w; h[4]=b.x;h[5]=b.y;h[6]=b.z;h[7]=b.w;
        c[0]=d.x;c[1]=d.y;c[2]=d.z;c[3]=d.w; c[4]=e.x;c[5]=e.y;c[6]=e.z;c[7]=e.w;
    }
    const double invB = 1.0 / (double)B;
    #pragma unroll
    for (int u = 0; u < 8; ++u){
        const float mH = (float)(stats1[u]      * invB);
        const float eH = (float)(stats1[8 + u]  * invB);
        const float mC = (float)(stats1[16 + u] * invB);
        const float eC = (float)(stats1[24 + u] * invB);
        const float aH = gamma_h[u] * rsqrtf(eH - mH*mH + EPSV);
        const float aC = gamma_c[u] * rsqrtf(eC - mC*mC + EPSV);
        h[u] = fmaf(h[u], aH, beta_h[u] - mH*aH);
        c[u] = fmaf(c[u], aC, beta_c[u] - mC*aC);
    }
    // BN3 coefficients (uniform; live across the replay loop)
    const double invN = 1.0 / ((double)B * 14.0);
    float a3[8], b3[8];
    #pragma unroll
    for (int u = 0; u < 8; ++u){
        const float m3 = (float)(stats3[u]     * invN);
        const float e3 = (float)(stats3[8 + u] * invN);
        a3[u] = gamma3[u] * rsqrtf(e3 - m3*m3 + EPSV);
        b3[u] = beta3[u] - m3*a3[u];
    }

    // AR replay; store BN3-normalized h rows to lane-private LDS
    #pragma unroll 1
    for (int r = 0; r < 14; ++r){
        float z[32];
        #pragma unroll
        for (int col = 0; col < 32; ++col) z[col] = b1[col];
        #pragma unroll
        for (int e = 0; e < 8; ++e){
            const float hv = h[e];
            #pragma unroll
            for (int col = 0; col < 32; ++col) z[col] = fmaf(hv, W1[e*32 + col], z[col]);
            #pragma unroll
            for (int col = 0; col < 32; ++col) z[col] = fmaf(hv, U1[e*32 + col], z[col]);
        }
        #pragma unroll
        for (int u = 0; u < 8; ++u){
            c[u] = fmaf(sigm(z[8+u]), c[u], sigm(z[u]) * fmaxf(z[16+u], 0.f));
            h[u] = sigm(z[24+u]) * fmaxf(c[u], 0.f);
            bars[r][u][tid] = fmaf(h[u], a3[u], b3[u]);
        }
    }

    // backward output LSTM over reversed rows: step i consumes AR row 13-i
    float ho[4], co[4];
    #pragma unroll
    for (int u = 0; u < 4; ++u){ ho[u] = 0.f; co[u] = 0.f; }
    #pragma unroll 1
    for (int i = 0; i < 14; ++i){
        const int r = 13 - i;
        float be[8];
        #pragma unroll
        for (int e = 0; e < 8; ++e) be[e] = bars[r][e][tid];
        float z2[16];
        #pragma unroll
        for (int col = 0; col < 16; ++col) z2[col] = b2[col];
        #pragma unroll
        for (int e = 0; e < 8; ++e){
            const float bv = be[e];
            #pragma unroll
            for (int col = 0; col < 16; ++col) z2[col] = fmaf(bv, W2[e*16 + col], z2[col]);
        }
        #pragma unroll
        for (int e = 0; e < 4; ++e){
            const float hv = ho[e];
            #pragma unroll
            for (int col = 0; col < 16; ++col) z2[col] = fmaf(hv, U2[e*16 + col], z2[col]);
        }
        #pragma unroll
        for (int u = 0; u < 4; ++u){
            co[u] = fmaf(sigm(z2[4+u]), co[u], sigm(z2[u]) * fmaxf(z2[8+u], 0.f));
            ho[u] = sigm(z2[12+u]) * fmaxf(co[u], 0.f);
        }
        *reinterpret_cast<float4*>(out + s*56 + i*4) = make_float4(ho[0],ho[1],ho[2],ho[3]);
    }
}

extern "C" void kernel_launch(void* const* d_in, const int* in_sizes, int n_in,
                              void* d_out, int out_size, void* d_ws, size_t ws_size,
                              hipStream_t stream)
{
    const float* noise   = (const float*)d_in[0];
    const float* W0      = (const float*)d_in[1];
    const float* U0      = (const float*)d_in[2];
    const float* b0      = (const float*)d_in[3];
    const float* gamma_h = (const float*)d_in[4];
    const float* beta_h  = (const float*)d_in[5];
    const float* gamma_c = (const float*)d_in[6];
    const float* beta_c  = (const float*)d_in[7];
    const float* W1      = (const float*)d_in[8];
    const float* U1      = (const float*)d_in[9];
    const float* b1      = (const float*)d_in[10];
    const float* gamma3  = (const float*)d_in[11];
    const float* beta3   = (const float*)d_in[12];
    const float* W2      = (const float*)d_in[13];
    const float* U2      = (const float*)d_in[14];
    const float* b2      = (const float*)d_in[15];

    const int B = in_sizes[0] / (32 * 16);   // 65536
    double* stats1 = (double*)d_ws;          // 32 doubles: Sh[8],Sh2[8],Sc[8],Sc2[8]
    double* stats3 = stats1 + 32;            // 16 doubles: Sb[8],Sb2[8]
    float* Hbuf = (float*)((char*)d_ws + 512);
    float* Cbuf = Hbuf + (size_t)B * 8;

    hipMemsetAsync(d_ws, 0, 48 * sizeof(double), stream);
    k1_lstm0<<<B/256, 256, 0, stream>>>(noise, W0, U0, b0, Hbuf, Cbuf, stats1);
    k2_ar  <<<B/256, 256, 0, stream>>>(Hbuf, Cbuf, stats1, gamma_h, beta_h, gamma_c, beta_c,
                                       W1, U1, b1, stats3, B);
    k3_out <<<B/64, 64, 0, stream>>>(Hbuf, Cbuf, stats1, stats3, gamma_h, beta_h,
                                     gamma_c, beta_c, W1, U1, b1, gamma3, beta3,
                                     W2, U2, b2, (float*)d_out, B);
}

// Round 7
// 188.807 us; speedup vs baseline: 1.1974x; 1.1974x over previous
//
#include <hip/hip_runtime.h>
#include <hip/hip_bf16.h>

#define EPSV 1e-3f

__device__ __forceinline__ float rcp_fast(float x){ return __builtin_amdgcn_rcpf(x); }
__device__ __forceinline__ float sigm(float x){ return rcp_fast(1.f + __expf(-x)); }
__device__ __forceinline__ float tanh_fast(float x){
    float e = __expf(2.f * x);
    return 1.f - 2.f * rcp_fast(e + 1.f);
}
#define KEEP(x) asm volatile("" : "+v"(x))

// ds_swizzle BitMode: src_lane = (lane & AND) | OR   (within 32-lane half)
template<int OR, int AND>
__device__ __forceinline__ float swz(float v){
    return __int_as_float(__builtin_amdgcn_ds_swizzle(__float_as_int(v), (OR << 5) | AND));
}
// 8-lane-group broadcast (K2/K3): src = (lane & 0x18) | K
template<int K>
__device__ __forceinline__ float bc8(float v){
    return __int_as_float(__builtin_amdgcn_ds_swizzle(__float_as_int(v), (K << 5) | 0x18));
}
#define BC8_ALL(dst, src) do { \
    dst[0]=bc8<0>(src); dst[1]=bc8<1>(src); dst[2]=bc8<2>(src); dst[3]=bc8<3>(src); \
    dst[4]=bc8<4>(src); dst[5]=bc8<5>(src); dst[6]=bc8<6>(src); dst[7]=bc8<7>(src); } while(0)
// 16-lane-group broadcast of unit e's h: src = (lane & 0x10) | e
#define BCAST16(dst, src) do { \
    dst[0]=swz<0,0x10>(src); dst[1]=swz<1,0x10>(src); dst[2]=swz<2,0x10>(src); dst[3]=swz<3,0x10>(src); \
    dst[4]=swz<4,0x10>(src); dst[5]=swz<5,0x10>(src); dst[6]=swz<6,0x10>(src); dst[7]=swz<7,0x10>(src); } while(0)

// ========== K1: stage-1 LSTM (tanh), 16 lanes/sample, 2 gate-cols/lane ======
// lane l<8 owns cols {l, l+16} = (i_u, g_u) of unit u=l  -> sigm(i)*tanh(g) local
// lane l>=8 owns cols {l, l+16} = (f_u, o_u) of unit u=l-8
// weights/lane = 50 regs -> total demand ~90, fits 128-reg budget natively.
__global__ __launch_bounds__(256)
__attribute__((amdgpu_waves_per_eu(2, 4)))
void k1_lstm0(const float* __restrict__ noise, const float* __restrict__ W0,
              const float* __restrict__ U0, const float* __restrict__ b0,
              float* __restrict__ Hbuf, float* __restrict__ Cbuf,
              double* __restrict__ stats1)
{
    const int tid = threadIdx.x;
    const int l = tid & 15;
    const size_t s = (size_t)blockIdx.x * 16 + (tid >> 4);

    float wa[16], wb[16], ua[8], ub[8];
    #pragma unroll
    for (int f = 0; f < 16; ++f){ wa[f] = W0[f*32 + l]; wb[f] = W0[f*32 + l + 16]; }
    #pragma unroll
    for (int e = 0; e < 8; ++e){ ua[e] = U0[e*32 + l]; ub[e] = U0[e*32 + l + 16]; }
    float ba = b0[l], bb = b0[l + 16];
    #pragma unroll
    for (int f = 0; f < 16; ++f){ KEEP(wa[f]); KEEP(wb[f]); }
    #pragma unroll
    for (int e = 0; e < 8; ++e){ KEEP(ua[e]); KEEP(ub[e]); }
    KEEP(ba); KEEP(bb);

    // z1 activation: l<8 -> tanh(z)=2*sigm(2z)-1 ; l>=8 -> sigm(z)
    const float k1s = (l < 8) ? -2.f : -1.f;
    const float m1  = (l < 8) ?  2.f :  1.f;
    const float n1  = (l < 8) ? -1.f :  0.f;

    const float4* __restrict__ xr = reinterpret_cast<const float4*>(noise + s * 512);

    float h = 0.f, c = 0.f, hall[8];
    #pragma unroll
    for (int e = 0; e < 8; ++e) hall[e] = 0.f;

    #pragma unroll 1
    for (int t = 0; t < 32; ++t){
        float4 p0 = xr[t*4+0], p1 = xr[t*4+1], p2 = xr[t*4+2], p3 = xr[t*4+3];
        float z0 = ba, z1 = bb;
        #pragma unroll
        for (int e = 0; e < 8; ++e){ z0 = fmaf(hall[e], ua[e], z0); z1 = fmaf(hall[e], ub[e], z1); }
        const float x[16] = {p0.x,p0.y,p0.z,p0.w, p1.x,p1.y,p1.z,p1.w,
                             p2.x,p2.y,p2.z,p2.w, p3.x,p3.y,p3.z,p3.w};
        #pragma unroll
        for (int f = 0; f < 16; ++f){ z0 = fmaf(x[f], wa[f], z0); z1 = fmaf(x[f], wb[f], z1); }
        const float a0 = sigm(z0);                                        // σ(i) | σ(f)
        const float a1 = fmaf(rcp_fast(1.f + __expf(z1 * k1s)), m1, n1);  // tanh(g) | σ(o)
        const float fv = swz<8, 0x17>(a0);   // σ(f_u) delivered to lane u
        const float ov = swz<8, 0x17>(a1);   // σ(o_u) delivered to lane u
        c = fmaf(fv, c, a0 * a1);            // lower lanes: σ(f)c + σ(i)tanh(g)
        h = ov * tanh_fast(c);               // upper lanes: bounded garbage
        BCAST16(hall, h);                    // h of units 0..7 (from lanes 0..7)
    }

    if (l < 8){ Hbuf[s*8 + l] = h; Cbuf[s*8 + l] = c; }

    // BN1 stats: sum over the wave's 4 samples, then block, then atomics
    float v0 = h, v1 = h*h, v2 = c, v3 = c*c;
    v0 += __shfl_xor(v0,16); v0 += __shfl_xor(v0,32);
    v1 += __shfl_xor(v1,16); v1 += __shfl_xor(v1,32);
    v2 += __shfl_xor(v2,16); v2 += __shfl_xor(v2,32);
    v3 += __shfl_xor(v3,16); v3 += __shfl_xor(v3,32);
    __shared__ float red[4][32];
    const int wv = tid >> 6, ln = tid & 63;
    if (ln < 8){ red[wv][ln] = v0; red[wv][8+ln] = v1; red[wv][16+ln] = v2; red[wv][24+ln] = v3; }
    __syncthreads();
    if (tid < 32){
        const float acc = red[0][tid] + red[1][tid] + red[2][tid] + red[3][tid];
        atomicAdd(stats1 + tid, (double)acc);
    }
}

// ========== K2: BN1-apply + 14-step AR LSTM (relu), BN3 sums (8-lane) =======
__global__ __launch_bounds__(256) void k2_ar(
    const float* __restrict__ Hbuf, const float* __restrict__ Cbuf,
    const double* __restrict__ stats1,
    const float* __restrict__ gamma_h, const float* __restrict__ beta_h,
    const float* __restrict__ gamma_c, const float* __restrict__ beta_c,
    const float* __restrict__ W1, const float* __restrict__ U1, const float* __restrict__ b1,
    double* __restrict__ stats3, int B)
{
    const int tid = threadIdx.x;
    const int d = tid & 7;
    const double invB = 1.0 / (double)B;
    const float meanH = (float)(stats1[d]      * invB);
    const float eH2   = (float)(stats1[8 + d]  * invB);
    const float meanC = (float)(stats1[16 + d] * invB);
    const float eC2   = (float)(stats1[24 + d] * invB);
    const float aH = gamma_h[d] * rsqrtf(eH2 - meanH*meanH + EPSV);
    const float aC = gamma_c[d] * rsqrtf(eC2 - meanC*meanC + EPSV);
    float h = fmaf(Hbuf[(size_t)blockIdx.x*256 + tid], aH, beta_h[d] - meanH*aH);
    float c = fmaf(Cbuf[(size_t)blockIdx.x*256 + tid], aC, beta_c[d] - meanC*aC);

    float wc[8][4], bcv[4];
    #pragma unroll
    for (int g = 0; g < 4; ++g) bcv[g] = b1[8*g + d];
    #pragma unroll
    for (int e = 0; e < 8; ++e)
        #pragma unroll
        for (int g = 0; g < 4; ++g) wc[e][g] = W1[e*32 + 8*g + d] + U1[e*32 + 8*g + d];

    float s1 = 0.f, s2 = 0.f;
    #pragma unroll
    for (int r = 0; r < 14; ++r){
        float hall[8]; BC8_ALL(hall, h);
        float z[4] = {bcv[0], bcv[1], bcv[2], bcv[3]};
        #pragma unroll
        for (int e = 0; e < 8; ++e)
            #pragma unroll
            for (int g = 0; g < 4; ++g) z[g] = fmaf(hall[e], wc[e][g], z[g]);
        c = sigm(z[1])*c + sigm(z[0])*fmaxf(z[2], 0.f);
        h = sigm(z[3])*fmaxf(c, 0.f);
        s1 += h; s2 = fmaf(h, h, s2);
    }
    s1 += __shfl_down(s1,32); s1 += __shfl_down(s1,16); s1 += __shfl_down(s1,8);
    s2 += __shfl_down(s2,32); s2 += __shfl_down(s2,16); s2 += __shfl_down(s2,8);
    __shared__ float red[2][4][8];
    const int w = tid >> 6;
    if ((tid & 63) < 8){ red[0][w][d] = s1; red[1][w][d] = s2; }
    __syncthreads();
    if (tid < 16){
        const int st = tid >> 3, dd = tid & 7;
        float acc = red[st][0][dd] + red[st][1][dd] + red[st][2][dd] + red[st][3][dd];
        atomicAdd(stats3 + st*8 + dd, (double)acc);
    }
}

// ========== K3: AR replay + BN3 + output LSTM (8->4), 8-lane ================
__global__ __launch_bounds__(256)
__attribute__((amdgpu_waves_per_eu(2, 2)))
void k3_out(
    const float* __restrict__ Hbuf, const float* __restrict__ Cbuf,
    const double* __restrict__ stats1, const double* __restrict__ stats3,
    const float* __restrict__ gamma_h, const float* __restrict__ beta_h,
    const float* __restrict__ gamma_c, const float* __restrict__ beta_c,
    const float* __restrict__ W1, const float* __restrict__ U1, const float* __restrict__ b1,
    const float* __restrict__ gamma3, const float* __restrict__ beta3,
    const float* __restrict__ W2, const float* __restrict__ U2, const float* __restrict__ b2,
    float* __restrict__ out, int B)
{
    const int tid = threadIdx.x;
    const int d = tid & 7;
    const double invB = 1.0 / (double)B;
    const float meanH = (float)(stats1[d]      * invB);
    const float eH2   = (float)(stats1[8 + d]  * invB);
    const float meanC = (float)(stats1[16 + d] * invB);
    const float eC2   = (float)(stats1[24 + d] * invB);
    const float aH = gamma_h[d] * rsqrtf(eH2 - meanH*meanH + EPSV);
    const float aC = gamma_c[d] * rsqrtf(eC2 - meanC*meanC + EPSV);
    float h = fmaf(Hbuf[(size_t)blockIdx.x*256 + tid], aH, beta_h[d] - meanH*aH);
    float c = fmaf(Cbuf[(size_t)blockIdx.x*256 + tid], aC, beta_c[d] - meanC*aC);

    float wc[8][4], bcv[4];
    #pragma unroll
    for (int g = 0; g < 4; ++g) bcv[g] = b1[8*g + d];
    #pragma unroll
    for (int e = 0; e < 8; ++e)
        #pragma unroll
        for (int g = 0; g < 4; ++g) wc[e][g] = W1[e*32 + 8*g + d] + U1[e*32 + 8*g + d];
    #pragma unroll
    for (int e = 0; e < 8; ++e)
        #pragma unroll
        for (int g = 0; g < 4; ++g) KEEP(wc[e][g]);

    float barh[14];
    #pragma unroll
    for (int r = 0; r < 14; ++r){
        float hall[8]; BC8_ALL(hall, h);
        float z[4] = {bcv[0], bcv[1], bcv[2], bcv[3]};
        #pragma unroll
        for (int e = 0; e < 8; ++e)
            #pragma unroll
            for (int g = 0; g < 4; ++g) z[g] = fmaf(hall[e], wc[e][g], z[g]);
        c = sigm(z[1])*c + sigm(z[0])*fmaxf(z[2], 0.f);
        h = sigm(z[3])*fmaxf(c, 0.f);
        barh[r] = h;
    }
    const double invN = 1.0 / ((double)B * 14.0);
    const float mean3 = (float)(stats3[d]     * invN);
    const float e32   = (float)(stats3[8 + d] * invN);
    const float a3 = gamma3[d] * rsqrtf(e32 - mean3*mean3 + EPSV);
    const float b3 = beta3[d] - mean3*a3;
    #pragma unroll
    for (int r = 0; r < 14; ++r) barh[r] = fmaf(barh[r], a3, b3);

    const int q = d & 3;
    float w2c[8][4], u2c[4][4], b2v[4];
    #pragma unroll
    for (int g = 0; g < 4; ++g) b2v[g] = b2[4*g + q];
    #pragma unroll
    for (int e = 0; e < 8; ++e)
        #pragma unroll
        for (int g = 0; g < 4; ++g) w2c[e][g] = W2[e*16 + 4*g + q];
    #pragma unroll
    for (int e = 0; e < 4; ++e)
        #pragma unroll
        for (int g = 0; g < 4; ++g) u2c[e][g] = U2[e*16 + 4*g + q];
    #pragma unroll
    for (int e = 0; e < 8; ++e)
        #pragma unroll
        for (int g = 0; g < 4; ++g) KEEP(w2c[e][g]);
    #pragma unroll
    for (int e = 0; e < 4; ++e)
        #pragma unroll
        for (int g = 0; g < 4; ++g) KEEP(u2c[e][g]);

    float ho = 0.f, co = 0.f;
    const size_t obase = ((size_t)blockIdx.x*32 + (tid >> 3)) * 56;
    #pragma unroll
    for (int r = 0; r < 14; ++r){
        const float cur = barh[13 - r];
        float be[8]; BC8_ALL(be, cur);
        float h4[4];
        h4[0]=bc8<0>(ho); h4[1]=bc8<1>(ho); h4[2]=bc8<2>(ho); h4[3]=bc8<3>(ho);
        float z[4] = {b2v[0], b2v[1], b2v[2], b2v[3]};
        #pragma unroll
        for (int e = 0; e < 8; ++e)
            #pragma unroll
            for (int g = 0; g < 4; ++g) z[g] = fmaf(be[e], w2c[e][g], z[g]);
        #pragma unroll
        for (int e = 0; e < 4; ++e)
            #pragma unroll
            for (int g = 0; g < 4; ++g) z[g] = fmaf(h4[e], u2c[e][g], z[g]);
        co = sigm(z[1])*co + sigm(z[0])*fmaxf(z[2], 0.f);
        ho = sigm(z[3])*fmaxf(co, 0.f);
        if (d < 4) out[obase + r*4 + d] = ho;
    }
}

extern "C" void kernel_launch(void* const* d_in, const int* in_sizes, int n_in,
                              void* d_out, int out_size, void* d_ws, size_t ws_size,
                              hipStream_t stream)
{
    const float* noise   = (const float*)d_in[0];
    const float* W0      = (const float*)d_in[1];
    const float* U0      = (const float*)d_in[2];
    const float* b0      = (const float*)d_in[3];
    const float* gamma_h = (const float*)d_in[4];
    const float* beta_h  = (const float*)d_in[5];
    const float* gamma_c = (const float*)d_in[6];
    const float* beta_c  = (const float*)d_in[7];
    const float* W1      = (const float*)d_in[8];
    const float* U1      = (const float*)d_in[9];
    const float* b1      = (const float*)d_in[10];
    const float* gamma3  = (const float*)d_in[11];
    const float* beta3   = (const float*)d_in[12];
    const float* W2      = (const float*)d_in[13];
    const float* U2      = (const float*)d_in[14];
    const float* b2      = (const float*)d_in[15];

    const int B = in_sizes[0] / (32 * 16);   // 65536
    double* stats1 = (double*)d_ws;          // 32 doubles: Sh[8],Sh2[8],Sc[8],Sc2[8]
    double* stats3 = stats1 + 32;            // 16 doubles: Sb[8],Sb2[8]
    float* Hbuf = (float*)((char*)d_ws + 512);
    float* Cbuf = Hbuf + (size_t)B * 8;

    hipMemsetAsync(d_ws, 0, 48 * sizeof(double), stream);
    k1_lstm0<<<B/16, 256, 0, stream>>>(noise, W0, U0, b0, Hbuf, Cbuf, stats1);
    k2_ar  <<<B/32, 256, 0, stream>>>(Hbuf, Cbuf, stats1, gamma_h, beta_h, gamma_c, beta_c,
                                      W1, U1, b1, stats3, B);
    k3_out <<<B/32, 256, 0, stream>>>(Hbuf, Cbuf, stats1, stats3, gamma_h, beta_h,
                                      gamma_c, beta_c, W1, U1, b1, gamma3, beta3,
                                      W2, U2, b2, (float*)d_out, B);
}

// Round 9
// 158.642 us; speedup vs baseline: 1.4250x; 1.1901x over previous
//
#include <hip/hip_runtime.h>
#include <hip/hip_bf16.h>

#define EPSV 1e-3f

__device__ __forceinline__ float rcp_fast(float x){ return __builtin_amdgcn_rcpf(x); }
__device__ __forceinline__ float sigm(float x){ return rcp_fast(1.f + __expf(-x)); }
__device__ __forceinline__ float tanh_fast(float x){
    float e = __expf(2.f * x);
    return 1.f - 2.f * rcp_fast(e + 1.f);
}

// 8-lane-group broadcast: src_lane = (lane & 0x18) | K
template<int K>
__device__ __forceinline__ float bc8(float v){
    return __int_as_float(__builtin_amdgcn_ds_swizzle(__float_as_int(v), (K << 5) | 0x18));
}
#define BC8_ALL(dst, src) do { \
    dst[0]=bc8<0>(src); dst[1]=bc8<1>(src); dst[2]=bc8<2>(src); dst[3]=bc8<3>(src); \
    dst[4]=bc8<4>(src); dst[5]=bc8<5>(src); dst[6]=bc8<6>(src); dst[7]=bc8<7>(src); } while(0)

// ---------------- K1: stage-1 LSTM (tanh), 8 lanes per sample ----------------
// Weights live in LDS (transposed per-d slices, pad 68/36 floats -> the 8
// per-d ds_read_b128 addresses tile all 32 banks, 8-way broadcast = free).
// Re-read every step via imm-offset ds_read_b128: no address recompute, no
// vmcnt, no VGPR pressure (R1-R7: global-load weights always remat/spill).
__global__ __launch_bounds__(256) void k1_lstm0(
    const float* __restrict__ noise, const float* __restrict__ W0,
    const float* __restrict__ U0, const float* __restrict__ b0,
    float* __restrict__ Hbuf, float* __restrict__ Cbuf, double* __restrict__ stats1)
{
    __shared__ float lw[8*68];     // [d][f*4+g], slice stride 68 (272B, 16B-aligned)
    __shared__ float lu[8*36];     // [d][e*4+g], slice stride 36 (144B)
    __shared__ float red[4][4][8];

    const int tid = threadIdx.x;
    const int d = tid & 7;
    // 512 lw entries, 256 threads: each thread stages TWO (R8 bug: only one).
    {
        const int i0 = tid;
        const int dd0 = i0 & 7, fg0 = i0 >> 3, f0 = fg0 >> 2, g0 = fg0 & 3;
        lw[dd0*68 + fg0] = W0[f0*32 + 8*g0 + dd0];
        const int i1 = tid + 256;
        const int dd1 = i1 & 7, fg1 = i1 >> 3, f1 = fg1 >> 2, g1 = fg1 & 3;
        lw[dd1*68 + fg1] = W0[f1*32 + 8*g1 + dd1];
    }
    {
        const int dd = tid & 7, eg = tid >> 3, e = eg >> 2, g = eg & 3;
        lu[dd*36 + eg] = U0[e*32 + 8*g + dd];   // 256 entries, all threads
    }
    float b0v[4];
    #pragma unroll
    for (int g = 0; g < 4; ++g) b0v[g] = b0[8*g + d];
    __syncthreads();

    const float* wp = &lw[d*68];
    const float* up = &lu[d*36];
    const size_t b = (size_t)blockIdx.x * 32 + (tid >> 3);
    const float4* __restrict__ xrow = reinterpret_cast<const float4*>(noise + b * 512);

    float h = 0.f, c = 0.f;
    float4 q0 = xrow[0], q1 = xrow[1], q2 = xrow[2], q3 = xrow[3];
    #pragma unroll 2
    for (int t = 0; t < 32; ++t){
        const float x[16] = {q0.x,q0.y,q0.z,q0.w, q1.x,q1.y,q1.z,q1.w,
                             q2.x,q2.y,q2.z,q2.w, q3.x,q3.y,q3.z,q3.w};
        const int tn = (t + 1) & 31;
        q0 = xrow[tn*4+0]; q1 = xrow[tn*4+1]; q2 = xrow[tn*4+2]; q3 = xrow[tn*4+3];
        float hall[8]; BC8_ALL(hall, h);
        float z0 = b0v[0], z1 = b0v[1], z2 = b0v[2], z3 = b0v[3];
        #pragma unroll
        for (int f = 0; f < 16; ++f){
            const float4 w = *reinterpret_cast<const float4*>(wp + f*4);
            z0 = fmaf(x[f], w.x, z0); z1 = fmaf(x[f], w.y, z1);
            z2 = fmaf(x[f], w.z, z2); z3 = fmaf(x[f], w.w, z3);
        }
        #pragma unroll
        for (int e = 0; e < 8; ++e){
            const float4 u = *reinterpret_cast<const float4*>(up + e*4);
            z0 = fmaf(hall[e], u.x, z0); z1 = fmaf(hall[e], u.y, z1);
            z2 = fmaf(hall[e], u.z, z2); z3 = fmaf(hall[e], u.w, z3);
        }
        // gate order i,f,g,o
        c = fmaf(sigm(z1), c, sigm(z0) * tanh_fast(z2));
        h = sigm(z3) * tanh_fast(c);
    }
    Hbuf[(size_t)blockIdx.x*256 + tid] = h;   // == b*8 + d
    Cbuf[(size_t)blockIdx.x*256 + tid] = c;

    float v0 = h, v1 = h*h, v2 = c, v3 = c*c;
    v0 += __shfl_down(v0,32); v0 += __shfl_down(v0,16); v0 += __shfl_down(v0,8);
    v1 += __shfl_down(v1,32); v1 += __shfl_down(v1,16); v1 += __shfl_down(v1,8);
    v2 += __shfl_down(v2,32); v2 += __shfl_down(v2,16); v2 += __shfl_down(v2,8);
    v3 += __shfl_down(v3,32); v3 += __shfl_down(v3,16); v3 += __shfl_down(v3,8);
    const int w = tid >> 6;
    if ((tid & 63) < 8){ red[0][w][d]=v0; red[1][w][d]=v1; red[2][w][d]=v2; red[3][w][d]=v3; }
    __syncthreads();
    if (tid < 32){
        const int s = tid >> 3, dd = tid & 7;
        float acc = red[s][0][dd] + red[s][1][dd] + red[s][2][dd] + red[s][3][dd];
        atomicAdd(stats1 + s*8 + dd, (double)acc);
    }
}

// ---------------- K2: BN1-apply + 14-step AR LSTM (relu), BN3 sums -----------
__global__ __launch_bounds__(256) void k2_ar(
    const float* __restrict__ Hbuf, const float* __restrict__ Cbuf,
    const double* __restrict__ stats1,
    const float* __restrict__ gamma_h, const float* __restrict__ beta_h,
    const float* __restrict__ gamma_c, const float* __restrict__ beta_c,
    const float* __restrict__ W1, const float* __restrict__ U1, const float* __restrict__ b1,
    double* __restrict__ stats3, int B)
{
    __shared__ float ls[8*36];     // [d][e*4+g] = W1+U1
    __shared__ float red[2][4][8];
    const int tid = threadIdx.x;
    const int d = tid & 7;
    {
        const int dd = tid & 7, eg = tid >> 3, e = eg >> 2, g = eg & 3;
        ls[dd*36 + eg] = W1[e*32 + 8*g + dd] + U1[e*32 + 8*g + dd];
    }
    const double invB = 1.0 / (double)B;
    const float meanH = (float)(stats1[d]      * invB);
    const float eH2   = (float)(stats1[8 + d]  * invB);
    const float meanC = (float)(stats1[16 + d] * invB);
    const float eC2   = (float)(stats1[24 + d] * invB);
    const float aH = gamma_h[d] * rsqrtf(eH2 - meanH*meanH + EPSV);
    const float aC = gamma_c[d] * rsqrtf(eC2 - meanC*meanC + EPSV);
    float h = fmaf(Hbuf[(size_t)blockIdx.x*256 + tid], aH, beta_h[d] - meanH*aH);
    float c = fmaf(Cbuf[(size_t)blockIdx.x*256 + tid], aC, beta_c[d] - meanC*aC);
    float bcv[4];
    #pragma unroll
    for (int g = 0; g < 4; ++g) bcv[g] = b1[8*g + d];
    __syncthreads();
    const float* sp = &ls[d*36];

    float s1 = 0.f, s2 = 0.f;
    #pragma unroll
    for (int r = 0; r < 14; ++r){
        float hall[8]; BC8_ALL(hall, h);
        float z0 = bcv[0], z1 = bcv[1], z2 = bcv[2], z3 = bcv[3];
        #pragma unroll
        for (int e = 0; e < 8; ++e){
            const float4 u = *reinterpret_cast<const float4*>(sp + e*4);
            z0 = fmaf(hall[e], u.x, z0); z1 = fmaf(hall[e], u.y, z1);
            z2 = fmaf(hall[e], u.z, z2); z3 = fmaf(hall[e], u.w, z3);
        }
        c = fmaf(sigm(z1), c, sigm(z0) * fmaxf(z2, 0.f));
        h = sigm(z3) * fmaxf(c, 0.f);
        s1 += h; s2 = fmaf(h, h, s2);
    }
    s1 += __shfl_down(s1,32); s1 += __shfl_down(s1,16); s1 += __shfl_down(s1,8);
    s2 += __shfl_down(s2,32); s2 += __shfl_down(s2,16); s2 += __shfl_down(s2,8);
    const int w = tid >> 6;
    if ((tid & 63) < 8){ red[0][w][d] = s1; red[1][w][d] = s2; }
    __syncthreads();
    if (tid < 16){
        const int s = tid >> 3, dd = tid & 7;
        float acc = red[s][0][dd] + red[s][1][dd] + red[s][2][dd] + red[s][3][dd];
        atomicAdd(stats3 + s*8 + dd, (double)acc);
    }
}

// ---------------- K3: AR replay + BN3 + output LSTM (8->4) -------------------
__global__ __launch_bounds__(256) void k3_out(
    const float* __restrict__ Hbuf, const float* __restrict__ Cbuf,
    const double* __restrict__ stats1, const double* __restrict__ stats3,
    const float* __restrict__ gamma_h, const float* __restrict__ beta_h,
    const float* __restrict__ gamma_c, const float* __restrict__ beta_c,
    const float* __restrict__ W1, const float* __restrict__ U1, const float* __restrict__ b1,
    const float* __restrict__ gamma3, const float* __restrict__ beta3,
    const float* __restrict__ W2, const float* __restrict__ U2, const float* __restrict__ b2,
    float* __restrict__ out, int B)
{
    __shared__ float ls[8*36];     // W1+U1 slices
    __shared__ float lw2[4*36];    // [q][e*4+g] = W2[e*16+4g+q], e=0..7
    __shared__ float lu2[4*20];    // [q][e*4+g] = U2[e*16+4g+q], e=0..3
    const int tid = threadIdx.x;
    const int d = tid & 7;
    {
        const int dd = tid & 7, eg = tid >> 3, e = eg >> 2, g = eg & 3;
        ls[dd*36 + eg] = W1[e*32 + 8*g + dd] + U1[e*32 + 8*g + dd];
    }
    if (tid < 128){
        const int qq = tid & 3, eg = tid >> 2, e = eg >> 2, g = eg & 3;
        lw2[qq*36 + eg] = W2[e*16 + 4*g + qq];
    }
    if (tid < 64){
        const int qq = tid & 3, eg = tid >> 2, e = eg >> 2, g = eg & 3;
        lu2[qq*20 + eg] = U2[e*16 + 4*g + qq];
    }
    const double invB = 1.0 / (double)B;
    const float meanH = (float)(stats1[d]      * invB);
    const float eH2   = (float)(stats1[8 + d]  * invB);
    const float meanC = (float)(stats1[16 + d] * invB);
    const float eC2   = (float)(stats1[24 + d] * invB);
    const float aH = gamma_h[d] * rsqrtf(eH2 - meanH*meanH + EPSV);
    const float aC = gamma_c[d] * rsqrtf(eC2 - meanC*meanC + EPSV);
    float h = fmaf(Hbuf[(size_t)blockIdx.x*256 + tid], aH, beta_h[d] - meanH*aH);
    float c = fmaf(Cbuf[(size_t)blockIdx.x*256 + tid], aC, beta_c[d] - meanC*aC);
    float bcv[4];
    #pragma unroll
    for (int g = 0; g < 4; ++g) bcv[g] = b1[8*g + d];
    __syncthreads();
    const float* sp = &ls[d*36];

    float barh[14];
    #pragma unroll
    for (int r = 0; r < 14; ++r){
        float hall[8]; BC8_ALL(hall, h);
        float z0 = bcv[0], z1 = bcv[1], z2 = bcv[2], z3 = bcv[3];
        #pragma unroll
        for (int e = 0; e < 8; ++e){
            const float4 u = *reinterpret_cast<const float4*>(sp + e*4);
            z0 = fmaf(hall[e], u.x, z0); z1 = fmaf(hall[e], u.y, z1);
            z2 = fmaf(hall[e], u.z, z2); z3 = fmaf(hall[e], u.w, z3);
        }
        c = fmaf(sigm(z1), c, sigm(z0) * fmaxf(z2, 0.f));
        h = sigm(z3) * fmaxf(c, 0.f);
        barh[r] = h;
    }
    const double invN = 1.0 / ((double)B * 14.0);
    const float mean3 = (float)(stats3[d]     * invN);
    const float e32   = (float)(stats3[8 + d] * invN);
    const float a3 = gamma3[d] * rsqrtf(e32 - mean3*mean3 + EPSV);
    const float b3 = beta3[d] - mean3*a3;
    #pragma unroll
    for (int r = 0; r < 14; ++r) barh[r] = fmaf(barh[r], a3, b3);

    // output LSTM: Do=4; lanes 4-7 duplicate (q=d&3) so swizzles stay full-group
    const int q = d & 3;
    const float* w2p = &lw2[q*36];
    const float* u2p = &lu2[q*20];
    float b2v[4];
    #pragma unroll
    for (int g = 0; g < 4; ++g) b2v[g] = b2[4*g + q];

    float ho = 0.f, co = 0.f;
    const size_t obase = ((size_t)blockIdx.x*32 + (tid >> 3)) * 56;
    #pragma unroll
    for (int r = 0; r < 14; ++r){
        const float cur = barh[13 - r];            // bars = reversed hs
        float be[8]; BC8_ALL(be, cur);
        float h4[4];
        h4[0]=bc8<0>(ho); h4[1]=bc8<1>(ho); h4[2]=bc8<2>(ho); h4[3]=bc8<3>(ho);
        float z0 = b2v[0], z1 = b2v[1], z2 = b2v[2], z3 = b2v[3];
        #pragma unroll
        for (int e = 0; e < 8; ++e){
            const float4 w = *reinterpret_cast<const float4*>(w2p + e*4);
            z0 = fmaf(be[e], w.x, z0); z1 = fmaf(be[e], w.y, z1);
            z2 = fmaf(be[e], w.z, z2); z3 = fmaf(be[e], w.w, z3);
        }
        #pragma unroll
        for (int e = 0; e < 4; ++e){
            const float4 u = *reinterpret_cast<const float4*>(u2p + e*4);
            z0 = fmaf(h4[e], u.x, z0); z1 = fmaf(h4[e], u.y, z1);
            z2 = fmaf(h4[e], u.z, z2); z3 = fmaf(h4[e], u.w, z3);
        }
        co = fmaf(sigm(z1), co, sigm(z0) * fmaxf(z2, 0.f));
        ho = sigm(z3) * fmaxf(co, 0.f);
        if (d < 4) out[obase + r*4 + d] = ho;
    }
}

extern "C" void kernel_launch(void* const* d_in, const int* in_sizes, int n_in,
                              void* d_out, int out_size, void* d_ws, size_t ws_size,
                              hipStream_t stream)
{
    const float* noise   = (const float*)d_in[0];
    const float* W0      = (const float*)d_in[1];
    const float* U0      = (const float*)d_in[2];
    const float* b0      = (const float*)d_in[3];
    const float* gamma_h = (const float*)d_in[4];
    const float* beta_h  = (const float*)d_in[5];
    const float* gamma_c = (const float*)d_in[6];
    const float* beta_c  = (const float*)d_in[7];
    const float* W1      = (const float*)d_in[8];
    const float* U1      = (const float*)d_in[9];
    const float* b1      = (const float*)d_in[10];
    const float* gamma3  = (const float*)d_in[11];
    const float* beta3   = (const float*)d_in[12];
    const float* W2      = (const float*)d_in[13];
    const float* U2      = (const float*)d_in[14];
    const float* b2      = (const float*)d_in[15];

    const int B = in_sizes[0] / (32 * 16);   // 65536
    double* stats1 = (double*)d_ws;          // 32 doubles
    double* stats3 = stats1 + 32;            // 16 doubles
    float* Hbuf = (float*)((char*)d_ws + 512);
    float* Cbuf = Hbuf + (size_t)B * 8;

    hipMemsetAsync(d_ws, 0, 48 * sizeof(double), stream);
    const int nb = B / 32;  // 2048 blocks x 256 threads, 8 lanes/sample
    k1_lstm0<<<nb, 256, 0, stream>>>(noise, W0, U0, b0, Hbuf, Cbuf, stats1);
    k2_ar<<<nb, 256, 0, stream>>>(Hbuf, Cbuf, stats1, gamma_h, beta_h, gamma_c, beta_c,
                                  W1, U1, b1, stats3, B);
    k3_out<<<nb, 256, 0, stream>>>(Hbuf, Cbuf, stats1, stats3, gamma_h, beta_h, gamma_c, beta_c,
                                   W1, U1, b1, gamma3, beta3, W2, U2, b2, (float*)d_out, B);
}